// Round 1
// baseline (1173.554 us; speedup 1.0000x reference)
//
#include <hip/hip_runtime.h>

#define DIM 1536
#define NH 12
#define HD 128
#define S_LEN 5400
#define SPAD 5440      // 85*64  (flash tiles)
#define MPAD 5504      // 43*128 (GEMM M tiles)
#define NQKV 4608
#define EPS_NORM 1e-6f

typedef __bf16 bf16_t;
typedef __bf16 bf16x8 __attribute__((ext_vector_type(8)));
typedef __bf16 bf16x4 __attribute__((ext_vector_type(4)));
typedef float  f32x4  __attribute__((ext_vector_type(4)));

// async global->LDS, 16B per lane; LDS dest is wave-uniform base + lane*16
#define GLOAD_LDS16(gp, lp) __builtin_amdgcn_global_load_lds( \
    (__attribute__((address_space(1))) void*)(void*)(gp),     \
    (__attribute__((address_space(3))) void*)(lp), 16, 0, 0)

// ---------------- conversion kernels ----------------

__global__ __launch_bounds__(256) void cvt_x_kernel(const float* __restrict__ x,
                                                    bf16_t* __restrict__ xb) {
  size_t base = ((size_t)blockIdx.x * 256 + threadIdx.x) * 4;
  if (base >= (size_t)MPAD * DIM) return;
  size_t row = base / DIM;
  float4 v = make_float4(0.f, 0.f, 0.f, 0.f);
  if (row < S_LEN) v = *(const float4*)&x[base];
  bf16x4 o; o[0] = (__bf16)v.x; o[1] = (__bf16)v.y; o[2] = (__bf16)v.z; o[3] = (__bf16)v.w;
  *(bf16x4*)&xb[base] = o;
}

__global__ __launch_bounds__(256) void cvt_wqkv_kernel(const float* __restrict__ qw,
                                                       const float* __restrict__ kw,
                                                       const float* __restrict__ vw,
                                                       bf16_t* __restrict__ wb) {
  size_t base = ((size_t)blockIdx.x * 256 + threadIdx.x) * 4;
  if (base >= (size_t)NQKV * DIM) return;
  int row = (int)(base / DIM);
  int col = (int)(base - (size_t)row * DIM);
  const float* src; int rr = row;
  if (rr >= 3072)      { src = vw; rr -= 3072; }
  else if (rr >= 1536) { src = kw; rr -= 1536; }
  else                 { src = qw; }
  float4 v = *(const float4*)&src[(size_t)rr * DIM + col];
  bf16x4 o; o[0] = (__bf16)v.x; o[1] = (__bf16)v.y; o[2] = (__bf16)v.z; o[3] = (__bf16)v.w;
  *(bf16x4*)&wb[base] = o;
}

__global__ __launch_bounds__(256) void cvt_wo_kernel(const float* __restrict__ w,
                                                     bf16_t* __restrict__ wb) {
  size_t base = ((size_t)blockIdx.x * 256 + threadIdx.x) * 4;
  if (base >= (size_t)DIM * DIM) return;
  float4 v = *(const float4*)&w[base];
  bf16x4 o; o[0] = (__bf16)v.x; o[1] = (__bf16)v.y; o[2] = (__bf16)v.z; o[3] = (__bf16)v.w;
  *(bf16x4*)&wb[base] = o;
}

// ---------------- GEMM: C[M,N] = A[M,K] @ B[N,K]^T + bias ----------------
// m97-style: 128x128 tile, BK=32, 4 waves (2x2 of 64x64), global_load_lds w=16.

template<bool OUT_BF16>
__global__ __launch_bounds__(256) void gemm_bt_kernel(
    const bf16_t* __restrict__ A, const bf16_t* __restrict__ B, void* __restrict__ C,
    const float* __restrict__ bias0, const float* __restrict__ bias1,
    const float* __restrict__ bias2, int M, int N, int K, int Mvalid) {
  __shared__ bf16_t As[128 * 32];
  __shared__ bf16_t Bs[128 * 32];
  int tid = threadIdx.x;
  int lane = tid & 63, wave = tid >> 6, quad = lane >> 4, l16 = lane & 15;
  int m0 = blockIdx.y * 128, n0 = blockIdx.x * 128;
  int wm = (wave >> 1) * 64, wn = (wave & 1) * 64;
  const bf16_t* Ab = A + (size_t)m0 * K;
  const bf16_t* Bb = B + (size_t)n0 * K;
  f32x4 acc[4][4] = {};
  for (int kt = 0; kt < K; kt += 32) {
    __syncthreads();
#pragma unroll
    for (int i = 0; i < 2; i++) {
      int eo = (i * 256 + tid) * 8;       // 128x32 tile, 8 bf16 per lane-slot
      int row = eo >> 5, col = eo & 31;
      GLOAD_LDS16(Ab + (size_t)row * K + kt + col, &As[eo]);
      GLOAD_LDS16(Bb + (size_t)row * K + kt + col, &Bs[eo]);
    }
    __syncthreads();
    bf16x8 af[4], bfr[4];
#pragma unroll
    for (int i = 0; i < 4; i++)
      af[i] = *(const bf16x8*)&As[(wm + i * 16 + l16) * 32 + quad * 8];
#pragma unroll
    for (int j = 0; j < 4; j++)
      bfr[j] = *(const bf16x8*)&Bs[(wn + j * 16 + l16) * 32 + quad * 8];
#pragma unroll
    for (int i = 0; i < 4; i++)
#pragma unroll
      for (int j = 0; j < 4; j++)
        acc[i][j] = __builtin_amdgcn_mfma_f32_16x16x32_bf16(af[i], bfr[j], acc[i][j], 0, 0, 0);
  }
  // epilogue: C/D layout col=lane&15, row=quad*4+reg  [m89-verified]
#pragma unroll
  for (int j = 0; j < 4; j++) {
    int n = n0 + wn + j * 16 + l16;
    float bias = (n < 1536) ? bias0[n] : (n < 3072) ? bias1[n - 1536] : bias2[n - 3072];
#pragma unroll
    for (int i = 0; i < 4; i++) {
#pragma unroll
      for (int r = 0; r < 4; r++) {
        int m = m0 + wm + i * 16 + quad * 4 + r;
        float v = acc[i][j][r] + bias;
        if (OUT_BF16) {
          ((bf16_t*)C)[(size_t)m * N + n] = (__bf16)v;
        } else {
          if (m < Mvalid) ((float*)C)[(size_t)m * N + n] = v;
        }
      }
    }
  }
}

// ---------------- RMSNorm + RoPE for q,k ----------------

__global__ __launch_bounds__(256) void rope_qk_kernel(
    const bf16_t* __restrict__ qkv, const float* __restrict__ nqw,
    const float* __restrict__ nkw, const float* __restrict__ fcos,
    const float* __restrict__ fsin, bf16_t* __restrict__ qout,
    bf16_t* __restrict__ kout) {
  int s = blockIdx.x;              // 0..SPAD-1
  int tid = threadIdx.x;
  bool valid = s < S_LEN;
  int f = s / 900, hh = (s / 30) % 30, ww = s % 30;
  __shared__ float red[4];
  for (int which = 0; which < 2; which++) {
    const bf16_t* src = qkv + (size_t)s * NQKV + which * DIM;
    const float* nw = which ? nkw : nqw;
    bf16_t* dst = (which ? kout : qout) + (size_t)s * DIM;
    float v[6]; float ss = 0.f;
#pragma unroll
    for (int i = 0; i < 6; i++) {
      v[i] = valid ? (float)src[tid * 6 + i] : 0.f;
      ss += v[i] * v[i];
    }
#pragma unroll
    for (int off = 32; off >= 1; off >>= 1) ss += __shfl_down(ss, off);
    if ((tid & 63) == 0) red[tid >> 6] = ss;
    __syncthreads();
    float tot = red[0] + red[1] + red[2] + red[3];
    float rn = rsqrtf(tot * (1.f / DIM) + EPS_NORM);
    __syncthreads();   // protect red[] before next `which` iteration
#pragma unroll
    for (int i = 0; i < 3; i++) {
      int e0 = tid * 6 + 2 * i;
      int p = e0 >> 1;             // pair index; head = p>>6, cc = p&63
      int cc = p & 63;
      int pos = (cc < 22) ? f : (cc < 43) ? hh : ww;  // split [22,21,21]
      float c = fcos[pos * 64 + cc], sn = fsin[pos * 64 + cc];
      float xr = v[2 * i] * rn * nw[e0];
      float xi = v[2 * i + 1] * rn * nw[e0 + 1];
      dst[e0]     = (__bf16)(xr * c - xi * sn);
      dst[e0 + 1] = (__bf16)(xr * sn + xi * c);
    }
  }
}

// ---------------- V transpose: qkv v-part -> vt[h][d][s] ----------------

__global__ __launch_bounds__(256) void v_transpose_kernel(const bf16_t* __restrict__ qkv,
                                                          bf16_t* __restrict__ vt) {
  __shared__ bf16_t tile[64][136];   // +8 pad: 16B-aligned rows, broken bank stride
  int h = blockIdx.y, s0 = blockIdx.x * 64, tid = threadIdx.x;
#pragma unroll
  for (int it = 0; it < 4; it++) {
    int eo = (it * 256 + tid) * 8;   // 64x128 elements
    int row = eo >> 7, col = eo & 127;
    int s = s0 + row;
    bf16x8 val = {};
    if (s < S_LEN) val = *(const bf16x8*)&qkv[(size_t)s * NQKV + 3072 + h * HD + col];
    *(bf16x8*)&tile[row][col] = val;
  }
  __syncthreads();
  int d = tid & 127, j0 = (tid >> 7) * 32;
  bf16x8 outv[4];
#pragma unroll
  for (int b = 0; b < 4; b++)
#pragma unroll
    for (int j = 0; j < 8; j++) outv[b][j] = tile[j0 + b * 8 + j][d];
  size_t base = ((size_t)h * HD + d) * SPAD + s0 + j0;
#pragma unroll
  for (int b = 0; b < 4; b++) *(bf16x8*)&vt[base + b * 8] = outv[b];
}

// ---------------- flash attention ----------------
// grid (85 q-tiles, 12 heads), 256 threads; wave w owns q rows [w*16, w*16+16)

__global__ __launch_bounds__(256) void flash_attn_kernel(
    const bf16_t* __restrict__ q, const bf16_t* __restrict__ k,
    const bf16_t* __restrict__ vt, bf16_t* __restrict__ o) {
  __shared__ bf16_t Qs[64 * 128];
  __shared__ bf16_t Ks[64 * 128];
  __shared__ bf16_t Vs[128 * 64];   // [d][j]
  __shared__ bf16_t Ps[4][16 * 64]; // per-wave P
  int h = blockIdx.y;
  int s0 = blockIdx.x * 64;
  int tid = threadIdx.x, wave = tid >> 6, lane = tid & 63;
  int quad = lane >> 4, l16 = lane & 15;
#pragma unroll
  for (int i = 0; i < 4; i++) {
    int eo = (i * 256 + tid) * 8;
    int row = eo >> 7, col = eo & 127;
    GLOAD_LDS16(q + (size_t)(s0 + row) * DIM + h * HD + col, &Qs[eo]);
  }
  float m_i[4], l_i[4];
#pragma unroll
  for (int r = 0; r < 4; r++) { m_i[r] = -1e30f; l_i[r] = 0.f; }
  f32x4 oacc[8] = {};
  const float scale = 0.08838834764831845f;  // 1/sqrt(128)
  for (int kt = 0; kt < SPAD; kt += 64) {
    __syncthreads();
#pragma unroll
    for (int i = 0; i < 4; i++) {
      int eo = (i * 256 + tid) * 8;
      int row = eo >> 7, col = eo & 127;
      GLOAD_LDS16(k + (size_t)(kt + row) * DIM + h * HD + col, &Ks[eo]);
      int d2 = eo >> 6, j2 = eo & 63;
      GLOAD_LDS16(vt + ((size_t)h * HD + d2) * SPAD + kt + j2, &Vs[eo]);
    }
    __syncthreads();
    // S = Q K^T (this wave's 16 q-rows x 64 k-cols)
    bf16x8 aq[4];
#pragma unroll
    for (int ks = 0; ks < 4; ks++)
      aq[ks] = *(const bf16x8*)&Qs[(wave * 16 + l16) * 128 + ks * 32 + quad * 8];
    f32x4 sacc[4] = {};
#pragma unroll
    for (int ns = 0; ns < 4; ns++)
#pragma unroll
      for (int ks = 0; ks < 4; ks++) {
        bf16x8 bk = *(const bf16x8*)&Ks[(ns * 16 + l16) * 128 + ks * 32 + quad * 8];
        sacc[ns] = __builtin_amdgcn_mfma_f32_16x16x32_bf16(aq[ks], bk, sacc[ns], 0, 0, 0);
      }
    // scale + pad-mask + row stats (row = quad*4 + r)
    float rowmax[4] = {-1e30f, -1e30f, -1e30f, -1e30f};
#pragma unroll
    for (int ns = 0; ns < 4; ns++) {
      bool ok = (kt + ns * 16 + l16) < S_LEN;
#pragma unroll
      for (int r = 0; r < 4; r++) {
        float x = ok ? sacc[ns][r] * scale : -1e30f;
        sacc[ns][r] = x;
        rowmax[r] = fmaxf(rowmax[r], x);
      }
    }
#pragma unroll
    for (int off = 1; off < 16; off <<= 1)
#pragma unroll
      for (int r = 0; r < 4; r++)
        rowmax[r] = fmaxf(rowmax[r], __shfl_xor(rowmax[r], off));
    float alpha[4], rs[4];
#pragma unroll
    for (int r = 0; r < 4; r++) {
      float mn = fmaxf(m_i[r], rowmax[r]);
      alpha[r] = __expf(m_i[r] - mn);
      m_i[r] = mn;
      rs[r] = 0.f;
    }
#pragma unroll
    for (int ns = 0; ns < 4; ns++)
#pragma unroll
      for (int r = 0; r < 4; r++) {
        float p = __expf(sacc[ns][r] - m_i[r]);
        rs[r] += p;
        Ps[wave][(quad * 4 + r) * 64 + ns * 16 + l16] = (__bf16)p;
      }
#pragma unroll
    for (int off = 1; off < 16; off <<= 1)
#pragma unroll
      for (int r = 0; r < 4; r++) rs[r] += __shfl_xor(rs[r], off);
#pragma unroll
    for (int r = 0; r < 4; r++) l_i[r] = l_i[r] * alpha[r] + rs[r];
#pragma unroll
    for (int d = 0; d < 8; d++)
#pragma unroll
      for (int r = 0; r < 4; r++) oacc[d][r] *= alpha[r];
    // O += P V   (A = P in A-layout via LDS round-trip, B = V^T tile)
    bf16x8 ap[2];
    ap[0] = *(const bf16x8*)&Ps[wave][l16 * 64 + quad * 8];
    ap[1] = *(const bf16x8*)&Ps[wave][l16 * 64 + 32 + quad * 8];
#pragma unroll
    for (int d = 0; d < 8; d++)
#pragma unroll
      for (int ks = 0; ks < 2; ks++) {
        bf16x8 bv = *(const bf16x8*)&Vs[(d * 16 + l16) * 64 + ks * 32 + quad * 8];
        oacc[d] = __builtin_amdgcn_mfma_f32_16x16x32_bf16(ap[ks], bv, oacc[d], 0, 0, 0);
      }
  }
#pragma unroll
  for (int d = 0; d < 8; d++) {
#pragma unroll
    for (int r = 0; r < 4; r++) {
      int s = s0 + wave * 16 + quad * 4 + r;
      if (s < S_LEN) {
        float val = oacc[d][r] / l_i[r];
        o[(size_t)s * DIM + h * HD + d * 16 + l16] = (__bf16)val;
      }
    }
  }
}

// ---------------- launch ----------------

extern "C" void kernel_launch(void* const* d_in, const int* in_sizes, int n_in,
                              void* d_out, int out_size, void* d_ws, size_t ws_size,
                              hipStream_t stream) {
  const float* x    = (const float*)d_in[0];
  const float* q_w  = (const float*)d_in[1];
  const float* q_b  = (const float*)d_in[2];
  const float* k_w  = (const float*)d_in[3];
  const float* k_b  = (const float*)d_in[4];
  const float* v_w  = (const float*)d_in[5];
  const float* v_b  = (const float*)d_in[6];
  const float* o_w  = (const float*)d_in[7];
  const float* o_b  = (const float*)d_in[8];
  const float* nqw  = (const float*)d_in[9];
  const float* nkw  = (const float*)d_in[10];
  const float* fcos = (const float*)d_in[11];
  const float* fsin = (const float*)d_in[12];

  char* ws = (char*)d_ws;
  // layout (bytes):
  //   0        : xb   bf16 MPAD*DIM   (16,908,288)  -- reused as vtb after GEMM1
  //   16908288 : wqkv bf16 NQKV*DIM   (14,155,776)
  //   31064064 : wob  bf16 DIM*DIM    ( 4,718,592)
  //   35782656 : qkv  bf16 MPAD*NQKV  (50,724,864)  -- reused as aob after rope/transpose
  //   86507520 : qb   bf16 SPAD*DIM   (16,711,680)
  //  103219200 : kb   bf16 SPAD*DIM   (16,711,680)  -> end 119,930,880
  bf16_t* xb   = (bf16_t*)(ws + 0);
  bf16_t* wqkv = (bf16_t*)(ws + 16908288);
  bf16_t* wob  = (bf16_t*)(ws + 31064064);
  bf16_t* qkv  = (bf16_t*)(ws + 35782656);
  bf16_t* qb   = (bf16_t*)(ws + 86507520);
  bf16_t* kb   = (bf16_t*)(ws + 103219200);
  bf16_t* vtb  = (bf16_t*)(ws + 0);         // alias xb (dead after GEMM1)
  bf16_t* aob  = (bf16_t*)(ws + 35782656);  // alias qkv (dead after rope+transpose)

  cvt_x_kernel<<<(MPAD * DIM / 4 + 255) / 256, 256, 0, stream>>>(x, xb);
  cvt_wqkv_kernel<<<(NQKV * DIM / 4 + 255) / 256, 256, 0, stream>>>(q_w, k_w, v_w, wqkv);
  cvt_wo_kernel<<<(DIM * DIM / 4 + 255) / 256, 256, 0, stream>>>(o_w, wob);

  gemm_bt_kernel<true><<<dim3(NQKV / 128, MPAD / 128), 256, 0, stream>>>(
      xb, wqkv, qkv, q_b, k_b, v_b, MPAD, NQKV, DIM, MPAD);

  rope_qk_kernel<<<SPAD, 256, 0, stream>>>(qkv, nqw, nkw, fcos, fsin, qb, kb);
  v_transpose_kernel<<<dim3(SPAD / 64, NH), 256, 0, stream>>>(qkv, vtb);

  flash_attn_kernel<<<dim3(SPAD / 64, NH), 256, 0, stream>>>(qb, kb, vtb, aob);

  gemm_bt_kernel<false><<<dim3(DIM / 128, MPAD / 128), 256, 0, stream>>>(
      aob, wob, d_out, o_b, o_b, o_b, MPAD, DIM, DIM, S_LEN);
}

// Round 2
// 712.696 us; speedup vs baseline: 1.6466x; 1.6466x over previous
//
#include <hip/hip_runtime.h>

#define DIM 1536
#define NH 12
#define HD 128
#define S_LEN 5400
#define SPAD 5440      // 85*64  (kv tiles)
#define MPAD 5504      // 43*128 (GEMM/flash q tiles)
#define NQKV 4608
#define EPS_NORM 1e-6f

typedef __bf16 bf16_t;
typedef __bf16 bf16x8 __attribute__((ext_vector_type(8)));
typedef __bf16 bf16x4 __attribute__((ext_vector_type(4)));
typedef float  f32x4  __attribute__((ext_vector_type(4)));

// async global->LDS, 16B per lane; LDS dest is wave-uniform base + lane*16
#define GLOAD_LDS16(gp, lp) __builtin_amdgcn_global_load_lds( \
    (__attribute__((address_space(1))) void*)(void*)(gp),     \
    (__attribute__((address_space(3))) void*)(lp), 16, 0, 0)

// ---------------- conversion kernels ----------------

__global__ __launch_bounds__(256) void cvt_x_kernel(const float* __restrict__ x,
                                                    bf16_t* __restrict__ xb) {
  size_t base = ((size_t)blockIdx.x * 256 + threadIdx.x) * 4;
  if (base >= (size_t)MPAD * DIM) return;
  size_t row = base / DIM;
  float4 v = make_float4(0.f, 0.f, 0.f, 0.f);
  if (row < S_LEN) v = *(const float4*)&x[base];
  bf16x4 o; o[0] = (__bf16)v.x; o[1] = (__bf16)v.y; o[2] = (__bf16)v.z; o[3] = (__bf16)v.w;
  *(bf16x4*)&xb[base] = o;
}

__global__ __launch_bounds__(256) void cvt_wqkv_kernel(const float* __restrict__ qw,
                                                       const float* __restrict__ kw,
                                                       const float* __restrict__ vw,
                                                       bf16_t* __restrict__ wb) {
  size_t base = ((size_t)blockIdx.x * 256 + threadIdx.x) * 4;
  if (base >= (size_t)NQKV * DIM) return;
  int row = (int)(base / DIM);
  int col = (int)(base - (size_t)row * DIM);
  const float* src; int rr = row;
  if (rr >= 3072)      { src = vw; rr -= 3072; }
  else if (rr >= 1536) { src = kw; rr -= 1536; }
  else                 { src = qw; }
  float4 v = *(const float4*)&src[(size_t)rr * DIM + col];
  bf16x4 o; o[0] = (__bf16)v.x; o[1] = (__bf16)v.y; o[2] = (__bf16)v.z; o[3] = (__bf16)v.w;
  *(bf16x4*)&wb[base] = o;
}

__global__ __launch_bounds__(256) void cvt_wo_kernel(const float* __restrict__ w,
                                                     bf16_t* __restrict__ wb) {
  size_t base = ((size_t)blockIdx.x * 256 + threadIdx.x) * 4;
  if (base >= (size_t)DIM * DIM) return;
  float4 v = *(const float4*)&w[base];
  bf16x4 o; o[0] = (__bf16)v.x; o[1] = (__bf16)v.y; o[2] = (__bf16)v.z; o[3] = (__bf16)v.w;
  *(bf16x4*)&wb[base] = o;
}

// ---------------- GEMM: C[M,N] = A[M,K] @ B[N,K]^T + bias ----------------

template<bool OUT_BF16>
__global__ __launch_bounds__(256) void gemm_bt_kernel(
    const bf16_t* __restrict__ A, const bf16_t* __restrict__ B, void* __restrict__ C,
    const float* __restrict__ bias0, const float* __restrict__ bias1,
    const float* __restrict__ bias2, int M, int N, int K, int Mvalid) {
  __shared__ bf16_t As[128 * 32];
  __shared__ bf16_t Bs[128 * 32];
  int tid = threadIdx.x;
  int lane = tid & 63, wave = tid >> 6, quad = lane >> 4, l16 = lane & 15;
  int m0 = blockIdx.y * 128, n0 = blockIdx.x * 128;
  int wm = (wave >> 1) * 64, wn = (wave & 1) * 64;
  const bf16_t* Ab = A + (size_t)m0 * K;
  const bf16_t* Bb = B + (size_t)n0 * K;
  f32x4 acc[4][4] = {};
  for (int kt = 0; kt < K; kt += 32) {
    __syncthreads();
#pragma unroll
    for (int i = 0; i < 2; i++) {
      int eo = (i * 256 + tid) * 8;       // 128x32 tile, 8 bf16 per lane-slot
      int row = eo >> 5, col = eo & 31;
      GLOAD_LDS16(Ab + (size_t)row * K + kt + col, &As[eo]);
      GLOAD_LDS16(Bb + (size_t)row * K + kt + col, &Bs[eo]);
    }
    __syncthreads();
    bf16x8 af[4], bfr[4];
#pragma unroll
    for (int i = 0; i < 4; i++)
      af[i] = *(const bf16x8*)&As[(wm + i * 16 + l16) * 32 + quad * 8];
#pragma unroll
    for (int j = 0; j < 4; j++)
      bfr[j] = *(const bf16x8*)&Bs[(wn + j * 16 + l16) * 32 + quad * 8];
#pragma unroll
    for (int i = 0; i < 4; i++)
#pragma unroll
      for (int j = 0; j < 4; j++)
        acc[i][j] = __builtin_amdgcn_mfma_f32_16x16x32_bf16(af[i], bfr[j], acc[i][j], 0, 0, 0);
  }
  // epilogue: C/D layout col=lane&15, row=quad*4+reg  [m89-verified]
#pragma unroll
  for (int j = 0; j < 4; j++) {
    int n = n0 + wn + j * 16 + l16;
    float bias = (n < 1536) ? bias0[n] : (n < 3072) ? bias1[n - 1536] : bias2[n - 3072];
#pragma unroll
    for (int i = 0; i < 4; i++) {
#pragma unroll
      for (int r = 0; r < 4; r++) {
        int m = m0 + wm + i * 16 + quad * 4 + r;
        float v = acc[i][j][r] + bias;
        if (OUT_BF16) {
          ((bf16_t*)C)[(size_t)m * N + n] = (__bf16)v;
        } else {
          if (m < Mvalid) ((float*)C)[(size_t)m * N + n] = v;
        }
      }
    }
  }
}

// ---------------- RMSNorm + RoPE for q,k ----------------
// q additionally pre-scaled by 1/sqrt(HD) so flash logits need no scale.

__global__ __launch_bounds__(256) void rope_qk_kernel(
    const bf16_t* __restrict__ qkv, const float* __restrict__ nqw,
    const float* __restrict__ nkw, const float* __restrict__ fcos,
    const float* __restrict__ fsin, bf16_t* __restrict__ qout,
    bf16_t* __restrict__ kout) {
  int s = blockIdx.x;              // 0..MPAD-1
  int tid = threadIdx.x;
  bool valid = s < S_LEN;
  int f = s / 900, hh = (s / 30) % 30, ww = s % 30;
  __shared__ float red[4];
  for (int which = 0; which < 2; which++) {
    const bf16_t* src = qkv + (size_t)s * NQKV + which * DIM;
    const float* nw = which ? nkw : nqw;
    bf16_t* dst = (which ? kout : qout) + (size_t)s * DIM;
    float osc = which ? 1.0f : 0.08838834764831845f;   // 1/sqrt(128) folded into q
    float v[6]; float ss = 0.f;
#pragma unroll
    for (int i = 0; i < 6; i++) {
      v[i] = valid ? (float)src[tid * 6 + i] : 0.f;
      ss += v[i] * v[i];
    }
#pragma unroll
    for (int off = 32; off >= 1; off >>= 1) ss += __shfl_down(ss, off);
    if ((tid & 63) == 0) red[tid >> 6] = ss;
    __syncthreads();
    float tot = red[0] + red[1] + red[2] + red[3];
    float rn = rsqrtf(tot * (1.f / DIM) + EPS_NORM);
    __syncthreads();   // protect red[] before next `which` iteration
#pragma unroll
    for (int i = 0; i < 3; i++) {
      int e0 = tid * 6 + 2 * i;
      int p = e0 >> 1;             // pair index; cc = p&63
      int cc = p & 63;
      int pos = (cc < 22) ? f : (cc < 43) ? hh : ww;  // split [22,21,21]
      float c = fcos[pos * 64 + cc], sn = fsin[pos * 64 + cc];
      float xr = v[2 * i] * rn * nw[e0];
      float xi = v[2 * i + 1] * rn * nw[e0 + 1];
      dst[e0]     = (__bf16)((xr * c - xi * sn) * osc);
      dst[e0 + 1] = (__bf16)((xr * sn + xi * c) * osc);
    }
  }
}

// ---------------- V transpose: qkv v-part -> vt[h][d][s] ----------------

__global__ __launch_bounds__(256) void v_transpose_kernel(const bf16_t* __restrict__ qkv,
                                                          bf16_t* __restrict__ vt) {
  __shared__ bf16_t tile[64][136];   // +8 pad
  int h = blockIdx.y, s0 = blockIdx.x * 64, tid = threadIdx.x;
#pragma unroll
  for (int it = 0; it < 4; it++) {
    int eo = (it * 256 + tid) * 8;   // 64x128 elements
    int row = eo >> 7, col = eo & 127;
    int s = s0 + row;
    bf16x8 val = {};
    if (s < S_LEN) val = *(const bf16x8*)&qkv[(size_t)s * NQKV + 3072 + h * HD + col];
    *(bf16x8*)&tile[row][col] = val;
  }
  __syncthreads();
  int d = tid & 127, j0 = (tid >> 7) * 32;
  bf16x8 outv[4];
#pragma unroll
  for (int b = 0; b < 4; b++)
#pragma unroll
    for (int j = 0; j < 8; j++) outv[b][j] = tile[j0 + b * 8 + j][d];
  size_t base = ((size_t)h * HD + d) * SPAD + s0 + j0;
#pragma unroll
  for (int b = 0; b < 4; b++) *(bf16x8*)&vt[base + b * 8] = outv[b];
}

// ---------------- flash attention (S^T = K Q^T orientation) ----------------
// grid (43 q-tiles of 128, 12 heads), 256 threads = 4 waves, wave owns 32 q.
// All LDS tiles stored with XOR chunk swizzle (16B chunk c at slot c^(row&7))
// so every MFMA fragment read covers all 32 banks uniformly.

__global__ __launch_bounds__(256, 2) void flash_attn_kernel(
    const bf16_t* __restrict__ q, const bf16_t* __restrict__ k,
    const bf16_t* __restrict__ vt, bf16_t* __restrict__ o) {
  __shared__ bf16_t Qs[128 * 128];   // 32 KB; reused as Ot in epilogue
  __shared__ bf16_t Ks[64 * 128];    // 16 KB
  __shared__ bf16_t Vs[128 * 64];    // 16 KB  [d][kv_j]
  __shared__ bf16_t PT[4][2][1024];  // 16 KB  per-wave-per-group P^T, k-chunked
  int h = blockIdx.y;
  int s0 = blockIdx.x * 128;
  int tid = threadIdx.x, w = tid >> 6, lane = tid & 63;
  int quad = lane >> 4, l16 = lane & 15;

  // ---- stage Q (swizzled): slot(row, pc) holds chunk c = (pc&8)|((pc&7)^(row&7))
#pragma unroll
  for (int it = 0; it < 8; it++) {
    int slot = it * 256 + tid;
    int row = slot >> 4, pc = slot & 15;
    int c = (pc & 8) | ((pc & 7) ^ (row & 7));
    GLOAD_LDS16(q + (size_t)(s0 + row) * DIM + h * HD + c * 8, &Qs[slot * 8]);
  }
  __syncthreads();

  // ---- hoist Q B-fragments (lane l16 = q col, k = quad*8+j within 32-blk)
  bf16x8 bq[2][4];
#pragma unroll
  for (int g = 0; g < 2; g++)
#pragma unroll
    for (int ks = 0; ks < 4; ks++) {
      int row = w * 32 + g * 16 + l16;
      int ch = ks * 4 + quad;
      int pc = (ch & 8) | ((ch & 7) ^ (l16 & 7));
      bq[g][ks] = *(const bf16x8*)&Qs[row * 128 + pc * 8];
    }

  float m_i[2] = {-1e30f, -1e30f}, l_i[2] = {0.f, 0.f};
  f32x4 oacc[2][8] = {};

  for (int kt = 0; kt < SPAD; kt += 64) {
    __syncthreads();
    // stage K tile 64x128 (16 chunks/row, swizzled)
#pragma unroll
    for (int it = 0; it < 4; it++) {
      int slot = it * 256 + tid;
      int row = slot >> 4, pc = slot & 15;
      int c = (pc & 8) | ((pc & 7) ^ (row & 7));
      GLOAD_LDS16(k + (size_t)(kt + row) * DIM + h * HD + c * 8, &Ks[slot * 8]);
    }
    // stage V^T tile 128x64 (8 chunks/row, swizzled)
#pragma unroll
    for (int it = 0; it < 4; it++) {
      int slot = it * 256 + tid;
      int d = slot >> 3, pc = slot & 7;
      int c = pc ^ (d & 7);
      GLOAD_LDS16(vt + ((size_t)h * HD + d) * SPAD + kt + c * 8, &Vs[slot * 8]);
    }
    __syncthreads();

    // ---- S^T = K Q^T : D[kv=quad*4+r (+16ns)][q=l16]
    f32x4 sacc[2][4] = {};
#pragma unroll
    for (int ns = 0; ns < 4; ns++) {
      bf16x8 ak[4];
#pragma unroll
      for (int ks = 0; ks < 4; ks++) {
        int row = ns * 16 + l16;
        int ch = ks * 4 + quad;
        int pc = (ch & 8) | ((ch & 7) ^ (l16 & 7));
        ak[ks] = *(const bf16x8*)&Ks[row * 128 + pc * 8];
      }
#pragma unroll
      for (int g = 0; g < 2; g++)
#pragma unroll
        for (int ks = 0; ks < 4; ks++)
          sacc[g][ns] = __builtin_amdgcn_mfma_f32_16x16x32_bf16(ak[ks], bq[g][ks], sacc[g][ns], 0, 0, 0);
    }

    bool full = (kt + 64 <= S_LEN);
    // ---- online softmax, per q-col (= per lane, replicated over quads)
#pragma unroll
    for (int g = 0; g < 2; g++) {
      if (!full) {
#pragma unroll
        for (int ns = 0; ns < 4; ns++)
#pragma unroll
          for (int r = 0; r < 4; r++)
            if (kt + ns * 16 + quad * 4 + r >= S_LEN) sacc[g][ns][r] = -1e30f;
      }
      float mx = -1e30f;
#pragma unroll
      for (int ns = 0; ns < 4; ns++)
#pragma unroll
        for (int r = 0; r < 4; r++) mx = fmaxf(mx, sacc[g][ns][r]);
      mx = fmaxf(mx, __shfl_xor(mx, 16));
      mx = fmaxf(mx, __shfl_xor(mx, 32));
      float mn = fmaxf(m_i[g], mx);
      float al = __expf(m_i[g] - mn);
      m_i[g] = mn;
      float rs = 0.f;
#pragma unroll
      for (int ns = 0; ns < 4; ns++) {
        bf16x4 pk;
#pragma unroll
        for (int r = 0; r < 4; r++) {
          float p = __expf(sacc[g][ns][r] - mn);
          rs += p;
          pk[r] = (__bf16)p;
        }
        // P^T chunked layout: [c=k>>2][q][k&3]; lane's 4 r's contiguous
        *(bf16x4*)&PT[w][g][(ns * 4 + quad) * 64 + l16 * 4] = pk;
      }
      rs += __shfl_xor(rs, 16);
      rs += __shfl_xor(rs, 32);
      l_i[g] = l_i[g] * al + rs;
#pragma unroll
      for (int dt = 0; dt < 8; dt++) oacc[g][dt] *= al;
    }

    // ---- O^T += V^T P^T : D[d=quad*4+r (+16dt)][q=l16]
#pragma unroll
    for (int ks = 0; ks < 2; ks++) {
      bf16x8 bp[2];
#pragma unroll
      for (int g = 0; g < 2; g++) {
        bf16x4 lo = *(const bf16x4*)&PT[w][g][(ks * 8 + quad * 2) * 64 + l16 * 4];
        bf16x4 hi = *(const bf16x4*)&PT[w][g][(ks * 8 + quad * 2 + 1) * 64 + l16 * 4];
#pragma unroll
        for (int j = 0; j < 4; j++) { bp[g][j] = lo[j]; bp[g][j + 4] = hi[j]; }
      }
#pragma unroll
      for (int dt = 0; dt < 8; dt++) {
        int ch = ks * 4 + quad;
        int pc = ch ^ (l16 & 7);
        bf16x8 av = *(const bf16x8*)&Vs[(dt * 16 + l16) * 64 + pc * 8];
#pragma unroll
        for (int g = 0; g < 2; g++)
          oacc[g][dt] = __builtin_amdgcn_mfma_f32_16x16x32_bf16(av, bp[g], oacc[g][dt], 0, 0, 0);
      }
    }
  }

  // ---- epilogue: O^T -> LDS (swizzled, transposed) -> coalesced global
  bf16_t* Ot = Qs;   // wave writes only its own q rows (its own Qs quarter)
#pragma unroll
  for (int g = 0; g < 2; g++) {
    float inv = 1.f / l_i[g];
#pragma unroll
    for (int dt = 0; dt < 8; dt++) {
      bf16x4 v;
#pragma unroll
      for (int r = 0; r < 4; r++) v[r] = (__bf16)(oacc[g][dt][r] * inv);
      int qrow = w * 32 + g * 16 + l16;
      int c = dt * 2 + (quad >> 1);
      int pc = (c & 8) | ((c & 7) ^ (l16 & 7));
      *(bf16x4*)&Ot[qrow * 128 + pc * 8 + (quad & 1) * 4] = v;
    }
  }
  __syncthreads();
#pragma unroll
  for (int i = 0; i < 8; i++) {
    int q_ = i * 16 + (tid >> 4);
    int cc = tid & 15;
    int pc = (cc & 8) | ((cc & 7) ^ (q_ & 7));
    bf16x8 val = *(const bf16x8*)&Ot[q_ * 128 + pc * 8];
    int s = s0 + q_;
    if (s < S_LEN) *(bf16x8*)&o[(size_t)s * DIM + h * HD + cc * 8] = val;
  }
}

// ---------------- launch ----------------

extern "C" void kernel_launch(void* const* d_in, const int* in_sizes, int n_in,
                              void* d_out, int out_size, void* d_ws, size_t ws_size,
                              hipStream_t stream) {
  const float* x    = (const float*)d_in[0];
  const float* q_w  = (const float*)d_in[1];
  const float* q_b  = (const float*)d_in[2];
  const float* k_w  = (const float*)d_in[3];
  const float* k_b  = (const float*)d_in[4];
  const float* v_w  = (const float*)d_in[5];
  const float* v_b  = (const float*)d_in[6];
  const float* o_w  = (const float*)d_in[7];
  const float* o_b  = (const float*)d_in[8];
  const float* nqw  = (const float*)d_in[9];
  const float* nkw  = (const float*)d_in[10];
  const float* fcos = (const float*)d_in[11];
  const float* fsin = (const float*)d_in[12];

  char* ws = (char*)d_ws;
  // layout (bytes):
  //   0         : xb   bf16 MPAD*DIM   (16,908,288)  -- reused as vtb after GEMM1
  //   16908288  : wqkv bf16 NQKV*DIM   (14,155,776)
  //   31064064  : wob  bf16 DIM*DIM    ( 4,718,592)
  //   35782656  : qkv  bf16 MPAD*NQKV  (50,724,864)  -- reused as aob
  //   86507520  : qb   bf16 MPAD*DIM   (16,908,288)
  //   103415808 : kb   bf16 MPAD*DIM   (16,908,288)  -> end 120,324,096
  bf16_t* xb   = (bf16_t*)(ws + 0);
  bf16_t* wqkv = (bf16_t*)(ws + 16908288);
  bf16_t* wob  = (bf16_t*)(ws + 31064064);
  bf16_t* qkv  = (bf16_t*)(ws + 35782656);
  bf16_t* qb   = (bf16_t*)(ws + 86507520);
  bf16_t* kb   = (bf16_t*)(ws + 103415808);
  bf16_t* vtb  = (bf16_t*)(ws + 0);         // alias xb (dead after GEMM1)
  bf16_t* aob  = (bf16_t*)(ws + 35782656);  // alias qkv (dead after rope+transpose)

  cvt_x_kernel<<<(MPAD * DIM / 4 + 255) / 256, 256, 0, stream>>>(x, xb);
  cvt_wqkv_kernel<<<(NQKV * DIM / 4 + 255) / 256, 256, 0, stream>>>(q_w, k_w, v_w, wqkv);
  cvt_wo_kernel<<<(DIM * DIM / 4 + 255) / 256, 256, 0, stream>>>(o_w, wob);

  gemm_bt_kernel<true><<<dim3(NQKV / 128, MPAD / 128), 256, 0, stream>>>(
      xb, wqkv, qkv, q_b, k_b, v_b, MPAD, NQKV, DIM, MPAD);

  rope_qk_kernel<<<MPAD, 256, 0, stream>>>(qkv, nqw, nkw, fcos, fsin, qb, kb);
  v_transpose_kernel<<<dim3(SPAD / 64, NH), 256, 0, stream>>>(qkv, vtb);

  flash_attn_kernel<<<dim3(MPAD / 128, NH), 256, 0, stream>>>(qb, kb, vtb, aob);

  gemm_bt_kernel<false><<<dim3(DIM / 128, MPAD / 128), 256, 0, stream>>>(
      aob, wob, d_out, o_b, o_b, o_b, MPAD, DIM, DIM, S_LEN);
}